// Round 2
// baseline (378.760 us; speedup 1.0000x reference)
//
#include <hip/hip_runtime.h>
#include <math.h>

#define T_LEN 4096
#define D_IN 128
#define HID 64
#define TR 64
#define CTX 64
#define KDIM 4096   // TR*CTX

// ws float offsets
#define OFF_GATED 0u
#define OFF_GO    262144u
#define OFF_SKIP  524288u
#define OFF_PART  786432u          // 8 * 262144 partials
#define OFF_FLAGS 2883584u         // 4096 ints
#define OFF_RE    2887680u         // 16777216
#define OFF_IM    19664896u

__device__ __forceinline__ float sigm(float x){ return 1.f/(1.f+expf(-x)); }

// ---------------------------------------------------------------- start flags
__global__ __launch_bounds__(256) void k_flags(const unsigned char* __restrict__ su8,
                                               const int* __restrict__ si32,
                                               int* __restrict__ flags)
{
    __shared__ int cnt;
    const int tid = threadIdx.x;
    if (tid == 0) cnt = 0;
    __syncthreads();
    int local = 0;
    // bytes at i%4!=0 are all zero iff storage is int32 (values 0/1)
    for (int i = tid; i < 4096; i += 256)
        if (i & 3) local += su8[i];
    if (local) atomicAdd(&cnt, local);
    __syncthreads();
    if (cnt > 0) {      // byte/bool storage
        for (int i = tid; i < 4096; i += 256) flags[i] = su8[i] ? 1 : 0;
    } else {            // int32 storage
        for (int i = tid; i < 4096; i += 256) flags[i] = si32[i] ? 1 : 0;
    }
}

// ---------------------------------------------------------------- MLP + gates
__global__ __launch_bounds__(256) void k_mlp(
    const float* __restrict__ x,
    const float* __restrict__ W1, const float* __restrict__ b1,
    const float* __restrict__ W2, const float* __restrict__ b2,
    const float* __restrict__ Wgi, const float* __restrict__ bgi,
    const float* __restrict__ Wp,  const float* __restrict__ bp,
    const float* __restrict__ Wgo, const float* __restrict__ bgo,
    const float* __restrict__ Wsk, const float* __restrict__ bsk,
    float* __restrict__ gated, float* __restrict__ go, float* __restrict__ sk)
{
    __shared__ float xs[16][128];
    __shared__ float hs[16][64];
    __shared__ float h2s[16][128];
    const int tid = threadIdx.x;
    const int t0 = blockIdx.x * 16;

    // stage x rows
#pragma unroll
    for (int u = 0; u < 2; ++u) {
        int f4 = tid * 2 + u; int r = f4 >> 5; int kq = (f4 & 31) << 2;
        *(float4*)&xs[r][kq] = *(const float4*)&x[(size_t)(t0 + r) * D_IN + kq];
    }
    __syncthreads();

    // h = relu(x@W1+b1): 16x64 items
#pragma unroll
    for (int it = 0; it < 4; ++it) {
        int item = tid + it * 256;
        int r = item >> 6, j = item & 63;
        float acc = b1[j];
#pragma unroll 8
        for (int k = 0; k < D_IN; ++k) acc += xs[r][k] * W1[k * HID + j];
        hs[r][j] = fmaxf(acc, 0.f);
    }
    __syncthreads();

    // h2 = h@W2+b2: 16x128 items
#pragma unroll
    for (int it = 0; it < 8; ++it) {
        int item = tid + it * 256;
        int r = item >> 7, j = item & 127;
        float acc = b2[j];
#pragma unroll 8
        for (int k = 0; k < HID; ++k) acc += hs[r][k] * W2[k * 128 + j];
        h2s[r][j] = acc;
    }
    __syncthreads();

    // gates: 16 rows x 3 tasks x 64 j
    for (int it = 0; it < 12; ++it) {
        int item = tid + it * 256;
        int r = item / 192; int rem = item - r * 192; int task = rem >> 6; int j = rem & 63;
        int t = t0 + r;
        if (task == 0) {
            float a0 = bgi[j], a1 = bp[j];
#pragma unroll 8
            for (int k = 0; k < 128; ++k) { float hv = h2s[r][k]; a0 += hv * Wgi[k * 64 + j]; a1 += hv * Wp[k * 64 + j]; }
            gated[t * 64 + j] = sigm(a0) * sigm(a1);
        } else if (task == 1) {
            float a0 = bgo[j];
#pragma unroll 8
            for (int k = 0; k < 128; ++k) a0 += h2s[r][k] * Wgo[k * 64 + j];
            go[t * 64 + j] = sigm(a0);
        } else {
            float a0 = bsk[j];
#pragma unroll 8
            for (int k = 0; k < 128; ++k) a0 += h2s[r][k] * Wsk[k * 64 + j];
            sk[t * 64 + j] = a0;
        }
    }
}

// ---------------------------------------------------------------- FFM scan (f64)
__global__ __launch_bounds__(64) void k_scan(
    const float* __restrict__ gated, const int* __restrict__ flags,
    const float* __restrict__ a, const float* __restrict__ b,
    const float* __restrict__ st0,
    float* __restrict__ re, float* __restrict__ im)
{
    const int m = blockIdx.x, c = threadIdx.x;
    const double ea = exp(-fabs((double)a[m]));
    const double bb = (double)b[c];
    const double lre = ea * cos(bb), lim = ea * sin(bb);
    double sre = (double)st0[(m * 64 + c) * 2];
    double sim = (double)st0[(m * 64 + c) * 2 + 1];
    __shared__ float gbuf[512];
    __shared__ int fbuf[512];
    for (int t0 = 0; t0 < T_LEN; t0 += 512) {
        for (int k = c; k < 512; k += 64) {
            gbuf[k] = gated[(size_t)(t0 + k) * 64 + m];
            fbuf[k] = flags[t0 + k];
        }
        __syncthreads();
        for (int j = 0; j < 512; ++j) {
            double g = (double)gbuf[j];
            if (fbuf[j]) { sre = g; sim = 0.0; }
            else {
                double nr = fma(sre, lre, fma(-sim, lim, g));
                double ni = fma(sre, lim, sim * lre);
                sre = nr; sim = ni;
            }
            size_t idx = (size_t)(t0 + j) * KDIM + m * 64 + c;
            re[idx] = (float)sre; im[idx] = (float)sim;
        }
        __syncthreads();
    }
}

// ---------------------------------------------------------------- z GEMM (K-split x8)
__global__ __launch_bounds__(512) void k_zgemm(
    const float* __restrict__ re, const float* __restrict__ im,
    const float* __restrict__ Wz, float* __restrict__ part)
{
    __shared__ float Ar[32][128], Ai[32][128], Br[32][64], Bi[32][64];
    const int tid = threadIdx.x;
    const int bx = blockIdx.x;
    const int mb = bx >> 3, kb = bx & 7;
    const int t0 = mb * 128;
    const int r0 = (tid >> 4) * 4, c0 = (tid & 15) * 4;
    const int kk_b = tid >> 4, h4 = (tid & 15) << 2;
    float acc[4][4] = {};

    for (int k0 = kb * 512; k0 < kb * 512 + 512; k0 += 32) {
        // stage A (transposed)
#pragma unroll
        for (int u = 0; u < 2; ++u) {
            int f4 = tid * 2 + u; int r = f4 >> 3; int kq = (f4 & 7) << 2;
            float4 vr = *(const float4*)&re[(size_t)(t0 + r) * KDIM + k0 + kq];
            float4 vi = *(const float4*)&im[(size_t)(t0 + r) * KDIM + k0 + kq];
            Ar[kq + 0][r] = vr.x; Ar[kq + 1][r] = vr.y; Ar[kq + 2][r] = vr.z; Ar[kq + 3][r] = vr.w;
            Ai[kq + 0][r] = vi.x; Ai[kq + 1][r] = vi.y; Ai[kq + 2][r] = vi.z; Ai[kq + 3][r] = vi.w;
        }
        // stage B: k = m*64+c -> Wz rows m*128+c (re) and m*128+64+c (im)
        {
            int k = k0 + kk_b; int mm = k >> 6, cc = k & 63;
            *(float4*)&Br[kk_b][h4] = *(const float4*)&Wz[(size_t)(mm * 128 + cc) * 64 + h4];
            *(float4*)&Bi[kk_b][h4] = *(const float4*)&Wz[(size_t)(mm * 128 + 64 + cc) * 64 + h4];
        }
        __syncthreads();
#pragma unroll 4
        for (int kk = 0; kk < 32; ++kk) {
            float4 ar = *(float4*)&Ar[kk][r0];
            float4 ai = *(float4*)&Ai[kk][r0];
            float4 br = *(float4*)&Br[kk][c0];
            float4 bi = *(float4*)&Bi[kk][c0];
            float arr[4] = {ar.x, ar.y, ar.z, ar.w}, aii[4] = {ai.x, ai.y, ai.z, ai.w};
            float brr[4] = {br.x, br.y, br.z, br.w}, bii[4] = {bi.x, bi.y, bi.z, bi.w};
#pragma unroll
            for (int i = 0; i < 4; ++i)
#pragma unroll
                for (int j = 0; j < 4; ++j)
                    acc[i][j] += arr[i] * brr[j] + aii[i] * bii[j];
        }
        __syncthreads();
    }
    float* pp = part + (size_t)kb * 262144;
#pragma unroll
    for (int i = 0; i < 4; ++i) {
        float4 v = {acc[i][0], acc[i][1], acc[i][2], acc[i][3]};
        *(float4*)&pp[(size_t)(t0 + r0 + i) * 64 + c0] = v;
    }
}

// ---------------------------------------------------------------- epilogue
__device__ __forceinline__ float wsum(float v) {
#pragma unroll
    for (int o = 32; o; o >>= 1) v += __shfl_xor(v, o, 64);
    return v;
}

__global__ __launch_bounds__(256) void k_epi(
    const float* __restrict__ part, const float* __restrict__ bz,
    const float* __restrict__ go, const float* __restrict__ sk,
    const float* __restrict__ W3, const float* __restrict__ b3,
    const float* __restrict__ W4, const float* __restrict__ b4,
    float* __restrict__ out)
{
    __shared__ float ob[4][64], hb[4][64];
    const int w = threadIdx.x >> 6, j = threadIdx.x & 63;
    const int t = blockIdx.x * 4 + w;
    float z = bz[j];
#pragma unroll
    for (int p = 0; p < 8; ++p) z += part[(size_t)p * 262144 + t * 64 + j];
    float g = go[t * 64 + j];
    float y = z * g;
    float mu = wsum(y) * 0.015625f;
    float d = y - mu;
    float var = wsum(d * d) * 0.015625f;
    float o = d * (1.f / sqrtf(var + 1e-6f)) + sk[t * 64 + j] * (1.f - g);
    ob[w][j] = o;
    __syncthreads();
    float acc = b3[j];
#pragma unroll 8
    for (int k = 0; k < 64; ++k) acc += ob[w][k] * W3[k * 64 + j];
    hb[w][j] = fmaxf(acc, 0.f);
    __syncthreads();
    float o1 = b4[j], o2 = b4[j + 64];
#pragma unroll 8
    for (int k = 0; k < 64; ++k) { float hv = hb[w][k]; o1 += hv * W4[k * 128 + j]; o2 += hv * W4[k * 128 + j + 64]; }
    out[(size_t)t * 128 + j] = o1;
    out[(size_t)t * 128 + j + 64] = o2;
}

// ---------------------------------------------------------------- final state (PLANAR: re plane then im plane)
__global__ void k_fin(const float* __restrict__ re, const float* __restrict__ im,
                      float* __restrict__ out)
{
    int i = blockIdx.x * 256 + threadIdx.x;
    out[524288 + i]        = re[(size_t)4095 * KDIM + i];
    out[524288 + 4096 + i] = im[(size_t)4095 * KDIM + i];
}

// ----------------------------------------------------------------
extern "C" void kernel_launch(void* const* d_in, const int* in_sizes, int n_in,
                              void* d_out, int out_size, void* d_ws, size_t ws_size,
                              hipStream_t stream)
{
    const float* x   = (const float*)d_in[0];
    const float* st0 = (const float*)d_in[1];
    const void*  start = d_in[2];
    const float* a  = (const float*)d_in[3];
    const float* b  = (const float*)d_in[4];
    const float* W1 = (const float*)d_in[5];  const float* b1 = (const float*)d_in[6];
    const float* W2 = (const float*)d_in[7];  const float* b2 = (const float*)d_in[8];
    const float* Wgi= (const float*)d_in[9];  const float* bgi= (const float*)d_in[10];
    const float* Wp = (const float*)d_in[11]; const float* bp = (const float*)d_in[12];
    const float* Wz = (const float*)d_in[13]; const float* bz = (const float*)d_in[14];
    const float* Wgo= (const float*)d_in[15]; const float* bgo= (const float*)d_in[16];
    const float* Wsk= (const float*)d_in[17]; const float* bsk= (const float*)d_in[18];
    const float* W3 = (const float*)d_in[19]; const float* b3 = (const float*)d_in[20];
    const float* W4 = (const float*)d_in[21]; const float* b4 = (const float*)d_in[22];

    float* ws    = (float*)d_ws;
    float* out   = (float*)d_out;
    float* gated = ws + OFF_GATED;
    float* go    = ws + OFF_GO;
    float* sk    = ws + OFF_SKIP;
    float* part  = ws + OFF_PART;
    int*   flags = (int*)(ws + OFF_FLAGS);
    float* re    = ws + OFF_RE;
    float* im    = ws + OFF_IM;

    hipLaunchKernelGGL(k_flags, dim3(1), dim3(256), 0, stream,
                       (const unsigned char*)start, (const int*)start, flags);
    hipLaunchKernelGGL(k_mlp, dim3(256), dim3(256), 0, stream,
                       x, W1, b1, W2, b2, Wgi, bgi, Wp, bp, Wgo, bgo, Wsk, bsk,
                       gated, go, sk);
    hipLaunchKernelGGL(k_scan, dim3(64), dim3(64), 0, stream,
                       gated, flags, a, b, st0, re, im);
    hipLaunchKernelGGL(k_zgemm, dim3(256), dim3(512), 0, stream, re, im, Wz, part);
    hipLaunchKernelGGL(k_epi, dim3(1024), dim3(256), 0, stream,
                       part, bz, go, sk, W3, b3, W4, b4, out);
    hipLaunchKernelGGL(k_fin, dim3(16), dim3(256), 0, stream, re, im, out);
}

// Round 3
// 226.729 us; speedup vs baseline: 1.6705x; 1.6705x over previous
//
#include <hip/hip_runtime.h>
#include <math.h>

#define T_LEN 4096
#define D_IN 128
#define HID 64
#define TR 64
#define CTX 64
#define KDIM 4096   // TR*CTX

// ws float offsets
#define OFF_GATED 0u
#define OFF_GO    262144u
#define OFF_SKIP  524288u
#define OFF_PART  786432u          // 8 * 262144 partials (also scan-carry scratch)
#define OFF_FLAGS 2883584u         // 4096 ints
#define OFF_RE    2887680u         // 16777216
#define OFF_IM    19664896u

// scan scratch inside part region (consumed before k_zgemm writes part)
#define CARRYB_OFF 0u        // float2[262144]  (2MB)  at part+0
#define CIN_OFF    524288u   // float2[262144]  (2MB)  at part+524288 floats
#define CHS_OFF    1048576u  // int[64]                at part+1048576 floats

__device__ __forceinline__ float sigm(float x){ return 1.f/(1.f+expf(-x)); }

// ---------------------------------------------------------------- start flags
__global__ __launch_bounds__(256) void k_flags(const unsigned char* __restrict__ su8,
                                               const int* __restrict__ si32,
                                               int* __restrict__ flags,
                                               int* __restrict__ chunkStart)
{
    __shared__ int cnt;
    const int tid = threadIdx.x;
    if (tid == 0) cnt = 0;
    __syncthreads();
    int local = 0;
    // bytes at i%4!=0 are all zero iff storage is int32 (values 0/1)
    for (int i = tid; i < 4096; i += 256)
        if (i & 3) local += su8[i];
    if (local) atomicAdd(&cnt, local);
    __syncthreads();
    if (cnt > 0) {      // byte/bool storage
        for (int i = tid; i < 4096; i += 256) flags[i] = su8[i] ? 1 : 0;
    } else {            // int32 storage
        for (int i = tid; i < 4096; i += 256) flags[i] = si32[i] ? 1 : 0;
    }
    __syncthreads();
    if (tid < 64) {
        int any = 0;
#pragma unroll 8
        for (int j = 0; j < 64; ++j) any |= flags[tid * 64 + j];
        chunkStart[tid] = any;
    }
}

// ---------------------------------------------------------------- MLP + gates
__global__ __launch_bounds__(256) void k_mlp(
    const float* __restrict__ x,
    const float* __restrict__ W1, const float* __restrict__ b1,
    const float* __restrict__ W2, const float* __restrict__ b2,
    const float* __restrict__ Wgi, const float* __restrict__ bgi,
    const float* __restrict__ Wp,  const float* __restrict__ bp,
    const float* __restrict__ Wgo, const float* __restrict__ bgo,
    const float* __restrict__ Wsk, const float* __restrict__ bsk,
    float* __restrict__ gated, float* __restrict__ go, float* __restrict__ sk)
{
    __shared__ float xs[16][128];
    __shared__ float hs[16][64];
    __shared__ float h2s[16][128];
    const int tid = threadIdx.x;
    const int t0 = blockIdx.x * 16;

    // stage x rows
#pragma unroll
    for (int u = 0; u < 2; ++u) {
        int f4 = tid * 2 + u; int r = f4 >> 5; int kq = (f4 & 31) << 2;
        *(float4*)&xs[r][kq] = *(const float4*)&x[(size_t)(t0 + r) * D_IN + kq];
    }
    __syncthreads();

    // h = relu(x@W1+b1): 16x64 items
#pragma unroll
    for (int it = 0; it < 4; ++it) {
        int item = tid + it * 256;
        int r = item >> 6, j = item & 63;
        float acc = b1[j];
#pragma unroll 8
        for (int k = 0; k < D_IN; ++k) acc += xs[r][k] * W1[k * HID + j];
        hs[r][j] = fmaxf(acc, 0.f);
    }
    __syncthreads();

    // h2 = h@W2+b2: 16x128 items
#pragma unroll
    for (int it = 0; it < 8; ++it) {
        int item = tid + it * 256;
        int r = item >> 7, j = item & 127;
        float acc = b2[j];
#pragma unroll 8
        for (int k = 0; k < HID; ++k) acc += hs[r][k] * W2[k * 128 + j];
        h2s[r][j] = acc;
    }
    __syncthreads();

    // gates: 16 rows x 3 tasks x 64 j
    for (int it = 0; it < 12; ++it) {
        int item = tid + it * 256;
        int r = item / 192; int rem = item - r * 192; int task = rem >> 6; int j = rem & 63;
        int t = t0 + r;
        if (task == 0) {
            float a0 = bgi[j], a1 = bp[j];
#pragma unroll 8
            for (int k = 0; k < 128; ++k) { float hv = h2s[r][k]; a0 += hv * Wgi[k * 64 + j]; a1 += hv * Wp[k * 64 + j]; }
            gated[t * 64 + j] = sigm(a0) * sigm(a1);
        } else if (task == 1) {
            float a0 = bgo[j];
#pragma unroll 8
            for (int k = 0; k < 128; ++k) a0 += h2s[r][k] * Wgo[k * 64 + j];
            go[t * 64 + j] = sigm(a0);
        } else {
            float a0 = bsk[j];
#pragma unroll 8
            for (int k = 0; k < 128; ++k) a0 += h2s[r][k] * Wsk[k * 64 + j];
            sk[t * 64 + j] = a0;
        }
    }
}

// ---------------------------------------------------------------- scan phase A: per-chunk local carries
// grid: 4096 blocks (ch = bx & 63, m = bx >> 6), 64 threads (c)
__global__ __launch_bounds__(64) void k_scanA(
    const float* __restrict__ gated, const int* __restrict__ flags,
    const float* __restrict__ a, const float* __restrict__ b,
    float2* __restrict__ carryB)
{
    const int bx = blockIdx.x;
    const int ch = bx & 63, m = bx >> 6;
    const int c = threadIdx.x;
    const int t0 = ch * 64;
    __shared__ float gb[64];
    __shared__ int fb[64];
    gb[c] = gated[(size_t)(t0 + c) * 64 + m];
    fb[c] = flags[t0 + c];
    __syncthreads();

    const double ea = exp(-fabs((double)a[m]));
    const double bb = (double)b[c];
    const double lre = ea * cos(bb), lim = ea * sin(bb);
    double sre = 0.0, sim = 0.0;
#pragma unroll 8
    for (int j = 0; j < 64; ++j) {
        double g = (double)gb[j];
        if (fb[j]) { sre = g; sim = 0.0; }
        else {
            double nr = fma(sre, lre, fma(-sim, lim, g));
            double ni = fma(sre, lim, sim * lre);
            sre = nr; sim = ni;
        }
    }
    carryB[(size_t)ch * KDIM + m * 64 + c] = make_float2((float)sre, (float)sim);
}

// ---------------------------------------------------------------- scan phase C: carry scan over chunks
// grid: 64 blocks (m), 64 threads (c)
__global__ __launch_bounds__(64) void k_scanC(
    const float2* __restrict__ carryB, const int* __restrict__ chunkStart,
    const float* __restrict__ a, const float* __restrict__ b,
    const float* __restrict__ st0,
    float2* __restrict__ cinArr)
{
    const int m = blockIdx.x, c = threadIdx.x;
    const double ea64 = exp(-64.0 * fabs((double)a[m]));
    const double bb = (double)b[c];
    const double l64re = ea64 * cos(64.0 * bb), l64im = ea64 * sin(64.0 * bb);
    double cre = (double)st0[(m * 64 + c) * 2];
    double cim = (double)st0[(m * 64 + c) * 2 + 1];
    for (int ch = 0; ch < 64; ++ch) {
        cinArr[(size_t)ch * KDIM + m * 64 + c] = make_float2((float)cre, (float)cim);
        float2 B = carryB[(size_t)ch * KDIM + m * 64 + c];
        if (chunkStart[ch]) { cre = (double)B.x; cim = (double)B.y; }
        else {
            double nr = fma(cre, l64re, fma(-cim, l64im, (double)B.x));
            double ni = fma(cre, l64im, fma(cim, l64re, (double)B.y));
            cre = nr; cim = ni;
        }
    }
}

// ---------------------------------------------------------------- scan phase B: seeded rerun, write state
// grid: 4096 blocks (ch = bx & 63, m = bx >> 6), 64 threads (c)
__global__ __launch_bounds__(64) void k_scanB(
    const float* __restrict__ gated, const int* __restrict__ flags,
    const float* __restrict__ a, const float* __restrict__ b,
    const float2* __restrict__ cinArr,
    float* __restrict__ re, float* __restrict__ im)
{
    const int bx = blockIdx.x;
    const int ch = bx & 63, m = bx >> 6;
    const int c = threadIdx.x;
    const int t0 = ch * 64;
    __shared__ float gb[64];
    __shared__ int fb[64];
    gb[c] = gated[(size_t)(t0 + c) * 64 + m];
    fb[c] = flags[t0 + c];
    __syncthreads();

    const double ea = exp(-fabs((double)a[m]));
    const double bb = (double)b[c];
    const double lre = ea * cos(bb), lim = ea * sin(bb);
    float2 cin = cinArr[(size_t)ch * KDIM + m * 64 + c];
    double sre = (double)cin.x, sim = (double)cin.y;
#pragma unroll 4
    for (int j = 0; j < 64; ++j) {
        double g = (double)gb[j];
        if (fb[j]) { sre = g; sim = 0.0; }
        else {
            double nr = fma(sre, lre, fma(-sim, lim, g));
            double ni = fma(sre, lim, sim * lre);
            sre = nr; sim = ni;
        }
        size_t idx = (size_t)(t0 + j) * KDIM + m * 64 + c;
        re[idx] = (float)sre; im[idx] = (float)sim;
    }
}

// ---------------------------------------------------------------- z GEMM (K-split x8)
__global__ __launch_bounds__(512) void k_zgemm(
    const float* __restrict__ re, const float* __restrict__ im,
    const float* __restrict__ Wz, float* __restrict__ part)
{
    __shared__ float Ar[32][128], Ai[32][128], Br[32][64], Bi[32][64];
    const int tid = threadIdx.x;
    const int bx = blockIdx.x;
    const int mb = bx >> 3, kb = bx & 7;
    const int t0 = mb * 128;
    const int r0 = (tid >> 4) * 4, c0 = (tid & 15) * 4;
    const int kk_b = tid >> 4, h4 = (tid & 15) << 2;
    float acc[4][4] = {};

    for (int k0 = kb * 512; k0 < kb * 512 + 512; k0 += 32) {
        // stage A (transposed)
#pragma unroll
        for (int u = 0; u < 2; ++u) {
            int f4 = tid * 2 + u; int r = f4 >> 3; int kq = (f4 & 7) << 2;
            float4 vr = *(const float4*)&re[(size_t)(t0 + r) * KDIM + k0 + kq];
            float4 vi = *(const float4*)&im[(size_t)(t0 + r) * KDIM + k0 + kq];
            Ar[kq + 0][r] = vr.x; Ar[kq + 1][r] = vr.y; Ar[kq + 2][r] = vr.z; Ar[kq + 3][r] = vr.w;
            Ai[kq + 0][r] = vi.x; Ai[kq + 1][r] = vi.y; Ai[kq + 2][r] = vi.z; Ai[kq + 3][r] = vi.w;
        }
        // stage B: k = m*64+c -> Wz rows m*128+c (re) and m*128+64+c (im)
        {
            int k = k0 + kk_b; int mm = k >> 6, cc = k & 63;
            *(float4*)&Br[kk_b][h4] = *(const float4*)&Wz[(size_t)(mm * 128 + cc) * 64 + h4];
            *(float4*)&Bi[kk_b][h4] = *(const float4*)&Wz[(size_t)(mm * 128 + 64 + cc) * 64 + h4];
        }
        __syncthreads();
#pragma unroll 4
        for (int kk = 0; kk < 32; ++kk) {
            float4 ar = *(float4*)&Ar[kk][r0];
            float4 ai = *(float4*)&Ai[kk][r0];
            float4 br = *(float4*)&Br[kk][c0];
            float4 bi = *(float4*)&Bi[kk][c0];
            float arr[4] = {ar.x, ar.y, ar.z, ar.w}, aii[4] = {ai.x, ai.y, ai.z, ai.w};
            float brr[4] = {br.x, br.y, br.z, br.w}, bii[4] = {bi.x, bi.y, bi.z, bi.w};
#pragma unroll
            for (int i = 0; i < 4; ++i)
#pragma unroll
                for (int j = 0; j < 4; ++j)
                    acc[i][j] += arr[i] * brr[j] + aii[i] * bii[j];
        }
        __syncthreads();
    }
    float* pp = part + (size_t)kb * 262144;
#pragma unroll
    for (int i = 0; i < 4; ++i) {
        float4 v = {acc[i][0], acc[i][1], acc[i][2], acc[i][3]};
        *(float4*)&pp[(size_t)(t0 + r0 + i) * 64 + c0] = v;
    }
}

// ---------------------------------------------------------------- epilogue
__device__ __forceinline__ float wsum(float v) {
#pragma unroll
    for (int o = 32; o; o >>= 1) v += __shfl_xor(v, o, 64);
    return v;
}

__global__ __launch_bounds__(256) void k_epi(
    const float* __restrict__ part, const float* __restrict__ bz,
    const float* __restrict__ go, const float* __restrict__ sk,
    const float* __restrict__ W3, const float* __restrict__ b3,
    const float* __restrict__ W4, const float* __restrict__ b4,
    float* __restrict__ out)
{
    __shared__ float ob[4][64], hb[4][64];
    const int w = threadIdx.x >> 6, j = threadIdx.x & 63;
    const int t = blockIdx.x * 4 + w;
    float z = bz[j];
#pragma unroll
    for (int p = 0; p < 8; ++p) z += part[(size_t)p * 262144 + t * 64 + j];
    float g = go[t * 64 + j];
    float y = z * g;
    float mu = wsum(y) * 0.015625f;
    float d = y - mu;
    float var = wsum(d * d) * 0.015625f;
    float o = d * (1.f / sqrtf(var + 1e-6f)) + sk[t * 64 + j] * (1.f - g);
    ob[w][j] = o;
    __syncthreads();
    float acc = b3[j];
#pragma unroll 8
    for (int k = 0; k < 64; ++k) acc += ob[w][k] * W3[k * 64 + j];
    hb[w][j] = fmaxf(acc, 0.f);
    __syncthreads();
    float o1 = b4[j], o2 = b4[j + 64];
#pragma unroll 8
    for (int k = 0; k < 64; ++k) { float hv = hb[w][k]; o1 += hv * W4[k * 128 + j]; o2 += hv * W4[k * 128 + j + 64]; }
    out[(size_t)t * 128 + j] = o1;
    out[(size_t)t * 128 + j + 64] = o2;
}

// ---------------------------------------------------------------- final state (planar: re plane then im plane)
__global__ void k_fin(const float* __restrict__ re, const float* __restrict__ im,
                      float* __restrict__ out)
{
    int i = blockIdx.x * 256 + threadIdx.x;
    out[524288 + i]        = re[(size_t)4095 * KDIM + i];
    out[524288 + 4096 + i] = im[(size_t)4095 * KDIM + i];
}

// ----------------------------------------------------------------
extern "C" void kernel_launch(void* const* d_in, const int* in_sizes, int n_in,
                              void* d_out, int out_size, void* d_ws, size_t ws_size,
                              hipStream_t stream)
{
    const float* x   = (const float*)d_in[0];
    const float* st0 = (const float*)d_in[1];
    const void*  start = d_in[2];
    const float* a  = (const float*)d_in[3];
    const float* b  = (const float*)d_in[4];
    const float* W1 = (const float*)d_in[5];  const float* b1 = (const float*)d_in[6];
    const float* W2 = (const float*)d_in[7];  const float* b2 = (const float*)d_in[8];
    const float* Wgi= (const float*)d_in[9];  const float* bgi= (const float*)d_in[10];
    const float* Wp = (const float*)d_in[11]; const float* bp = (const float*)d_in[12];
    const float* Wz = (const float*)d_in[13]; const float* bz = (const float*)d_in[14];
    const float* Wgo= (const float*)d_in[15]; const float* bgo= (const float*)d_in[16];
    const float* Wsk= (const float*)d_in[17]; const float* bsk= (const float*)d_in[18];
    const float* W3 = (const float*)d_in[19]; const float* b3 = (const float*)d_in[20];
    const float* W4 = (const float*)d_in[21]; const float* b4 = (const float*)d_in[22];

    float* ws    = (float*)d_ws;
    float* out   = (float*)d_out;
    float* gated = ws + OFF_GATED;
    float* go    = ws + OFF_GO;
    float* sk    = ws + OFF_SKIP;
    float* part  = ws + OFF_PART;
    int*   flags = (int*)(ws + OFF_FLAGS);
    float* re    = ws + OFF_RE;
    float* im    = ws + OFF_IM;

    float2* carryB = (float2*)(part + CARRYB_OFF);
    float2* cinArr = (float2*)(part + CIN_OFF);
    int*    chs    = (int*)(part + CHS_OFF);

    hipLaunchKernelGGL(k_flags, dim3(1), dim3(256), 0, stream,
                       (const unsigned char*)start, (const int*)start, flags, chs);
    hipLaunchKernelGGL(k_mlp, dim3(256), dim3(256), 0, stream,
                       x, W1, b1, W2, b2, Wgi, bgi, Wp, bp, Wgo, bgo, Wsk, bsk,
                       gated, go, sk);
    hipLaunchKernelGGL(k_scanA, dim3(4096), dim3(64), 0, stream,
                       gated, flags, a, b, carryB);
    hipLaunchKernelGGL(k_scanC, dim3(64), dim3(64), 0, stream,
                       carryB, chs, a, b, st0, cinArr);
    hipLaunchKernelGGL(k_scanB, dim3(4096), dim3(64), 0, stream,
                       gated, flags, a, b, cinArr, re, im);
    hipLaunchKernelGGL(k_zgemm, dim3(256), dim3(512), 0, stream, re, im, Wz, part);
    hipLaunchKernelGGL(k_epi, dim3(1024), dim3(256), 0, stream,
                       part, bz, go, sk, W3, b3, W4, b4, out);
    hipLaunchKernelGGL(k_fin, dim3(16), dim3(256), 0, stream, re, im, out);
}

// Round 4
// 146.228 us; speedup vs baseline: 2.5902x; 1.5505x over previous
//
#include <hip/hip_runtime.h>
#include <math.h>

#define T_LEN 4096
#define D_IN 128
#define HID 64
#define KDIM 4096   // TR*CTX
#define K2   8192   // re+im

// ws float offsets
#define OFF_GATED 0u
#define OFF_GO    262144u
#define OFF_SKIP  524288u
#define OFF_PART  786432u          // 4 * 262144 partials (also scan-carry scratch)
#define OFF_FLAGS 1835008u         // 4096 ints
#define OFF_CHS   1839104u         // 64 ints
#define OFF_WZT   1839168u         // 524288 bf16 = 262144 float slots
#define OFF_STBF  2101312u         // 4096*8192 bf16 = 16777216 float slots

typedef __attribute__((ext_vector_type(8))) short short8v;
typedef __attribute__((ext_vector_type(4))) float float4v;

__device__ __forceinline__ float sigm(float x){ return 1.f/(1.f+expf(-x)); }
__device__ __forceinline__ unsigned short f2bf(float x){
    unsigned int u = __float_as_uint(x);
    return (unsigned short)((u + 0x7FFFu + ((u >> 16) & 1u)) >> 16);
}

// ---------------------------------------------------------------- start flags
__global__ __launch_bounds__(256) void k_flags(const unsigned char* __restrict__ su8,
                                               const int* __restrict__ si32,
                                               int* __restrict__ flags,
                                               int* __restrict__ chunkStart)
{
    __shared__ int cnt;
    const int tid = threadIdx.x;
    if (tid == 0) cnt = 0;
    __syncthreads();
    int local = 0;
    for (int i = tid; i < 4096; i += 256)
        if (i & 3) local += su8[i];
    if (local) atomicAdd(&cnt, local);
    __syncthreads();
    if (cnt > 0) {      // byte/bool storage
        for (int i = tid; i < 4096; i += 256) flags[i] = su8[i] ? 1 : 0;
    } else {            // int32 storage
        for (int i = tid; i < 4096; i += 256) flags[i] = si32[i] ? 1 : 0;
    }
    __syncthreads();
    if (tid < 64) {
        int any = 0;
#pragma unroll 8
        for (int j = 0; j < 64; ++j) any |= flags[tid * 64 + j];
        chunkStart[tid] = any;
    }
}

// ---------------------------------------------------------------- Wz -> bf16 transposed/permuted  WzT[64][8192]
__global__ __launch_bounds__(256) void k_wzt(const float* __restrict__ Wz,
                                             unsigned short* __restrict__ wzt)
{
    int idx = (blockIdx.x * 256 + threadIdx.x) * 8;   // 524288 elems
    int j = idx >> 13, k0 = idx & 8191;
#pragma unroll
    for (int e = 0; e < 8; ++e) {
        int k = k0 + e;
        int km = k & 4095;
        int m = km >> 6, c = km & 63;
        int row = m * 128 + ((k >= 4096) ? 64 : 0) + c;
        wzt[(size_t)j * K2 + k] = f2bf(Wz[(size_t)row * 64 + j]);
    }
}

// ---------------------------------------------------------------- MLP + gates
__global__ __launch_bounds__(256) void k_mlp(
    const float* __restrict__ x,
    const float* __restrict__ W1, const float* __restrict__ b1,
    const float* __restrict__ W2, const float* __restrict__ b2,
    const float* __restrict__ Wgi, const float* __restrict__ bgi,
    const float* __restrict__ Wp,  const float* __restrict__ bp,
    const float* __restrict__ Wgo, const float* __restrict__ bgo,
    const float* __restrict__ Wsk, const float* __restrict__ bsk,
    float* __restrict__ gated, float* __restrict__ go, float* __restrict__ sk)
{
    __shared__ float xs[16][128];
    __shared__ float hs[16][64];
    __shared__ float h2s[16][128];
    const int tid = threadIdx.x;
    const int t0 = blockIdx.x * 16;

#pragma unroll
    for (int u = 0; u < 2; ++u) {
        int f4 = tid * 2 + u; int r = f4 >> 5; int kq = (f4 & 31) << 2;
        *(float4*)&xs[r][kq] = *(const float4*)&x[(size_t)(t0 + r) * D_IN + kq];
    }
    __syncthreads();

#pragma unroll
    for (int it = 0; it < 4; ++it) {
        int item = tid + it * 256;
        int r = item >> 6, j = item & 63;
        float acc = b1[j];
#pragma unroll 8
        for (int k = 0; k < D_IN; ++k) acc += xs[r][k] * W1[k * HID + j];
        hs[r][j] = fmaxf(acc, 0.f);
    }
    __syncthreads();

#pragma unroll
    for (int it = 0; it < 8; ++it) {
        int item = tid + it * 256;
        int r = item >> 7, j = item & 127;
        float acc = b2[j];
#pragma unroll 8
        for (int k = 0; k < HID; ++k) acc += hs[r][k] * W2[k * 128 + j];
        h2s[r][j] = acc;
    }
    __syncthreads();

    for (int it = 0; it < 12; ++it) {
        int item = tid + it * 256;
        int r = item / 192; int rem = item - r * 192; int task = rem >> 6; int j = rem & 63;
        int t = t0 + r;
        if (task == 0) {
            float a0 = bgi[j], a1 = bp[j];
#pragma unroll 8
            for (int k = 0; k < 128; ++k) { float hv = h2s[r][k]; a0 += hv * Wgi[k * 64 + j]; a1 += hv * Wp[k * 64 + j]; }
            gated[t * 64 + j] = sigm(a0) * sigm(a1);
        } else if (task == 1) {
            float a0 = bgo[j];
#pragma unroll 8
            for (int k = 0; k < 128; ++k) a0 += h2s[r][k] * Wgo[k * 64 + j];
            go[t * 64 + j] = sigm(a0);
        } else {
            float a0 = bsk[j];
#pragma unroll 8
            for (int k = 0; k < 128; ++k) a0 += h2s[r][k] * Wsk[k * 64 + j];
            sk[t * 64 + j] = a0;
        }
    }
}

// ---------------------------------------------------------------- scan A: per-chunk local carries
__global__ __launch_bounds__(64) void k_scanA(
    const float* __restrict__ gated, const int* __restrict__ flags,
    const float* __restrict__ a, const float* __restrict__ b,
    float2* __restrict__ carryB)
{
    const int bx = blockIdx.x;
    const int ch = bx & 63, m = bx >> 6;
    const int c = threadIdx.x;
    const int t0 = ch * 64;
    __shared__ float gb[64];
    __shared__ int fb[64];
    gb[c] = gated[(size_t)(t0 + c) * 64 + m];
    fb[c] = flags[t0 + c];
    __syncthreads();

    const double ea = exp(-fabs((double)a[m]));
    const double bb = (double)b[c];
    const double lre = ea * cos(bb), lim = ea * sin(bb);
    double sre = 0.0, sim = 0.0;
#pragma unroll 8
    for (int j = 0; j < 64; ++j) {
        double g = (double)gb[j];
        if (fb[j]) { sre = g; sim = 0.0; }
        else {
            double nr = fma(sre, lre, fma(-sim, lim, g));
            double ni = fma(sre, lim, sim * lre);
            sre = nr; sim = ni;
        }
    }
    carryB[(size_t)ch * KDIM + m * 64 + c] = make_float2((float)sre, (float)sim);
}

// ---------------------------------------------------------------- scan C: carry scan over chunks
__global__ __launch_bounds__(64) void k_scanC(
    const float2* __restrict__ carryB, const int* __restrict__ chunkStart,
    const float* __restrict__ a, const float* __restrict__ b,
    const float* __restrict__ st0,
    float2* __restrict__ cinArr)
{
    const int m = blockIdx.x, c = threadIdx.x;
    const double ea64 = exp(-64.0 * fabs((double)a[m]));
    const double bb = (double)b[c];
    const double l64re = ea64 * cos(64.0 * bb), l64im = ea64 * sin(64.0 * bb);
    double cre = (double)st0[(m * 64 + c) * 2];
    double cim = (double)st0[(m * 64 + c) * 2 + 1];
    for (int ch = 0; ch < 64; ++ch) {
        cinArr[(size_t)ch * KDIM + m * 64 + c] = make_float2((float)cre, (float)cim);
        float2 B = carryB[(size_t)ch * KDIM + m * 64 + c];
        if (chunkStart[ch]) { cre = (double)B.x; cim = (double)B.y; }
        else {
            double nr = fma(cre, l64re, fma(-cim, l64im, (double)B.x));
            double ni = fma(cre, l64im, fma(cim, l64re, (double)B.y));
            cre = nr; cim = ni;
        }
    }
}

// ---------------------------------------------------------------- scan B: seeded rerun, write bf16 state (+ final state f32)
__global__ __launch_bounds__(64) void k_scanB(
    const float* __restrict__ gated, const int* __restrict__ flags,
    const float* __restrict__ a, const float* __restrict__ b,
    const float2* __restrict__ cinArr,
    unsigned short* __restrict__ stbf,
    float* __restrict__ out)
{
    const int bx = blockIdx.x;
    const int ch = bx & 63, m = bx >> 6;
    const int c = threadIdx.x;
    const int t0 = ch * 64;
    __shared__ float gb[64];
    __shared__ int fb[64];
    gb[c] = gated[(size_t)(t0 + c) * 64 + m];
    fb[c] = flags[t0 + c];
    __syncthreads();

    const double ea = exp(-fabs((double)a[m]));
    const double bb = (double)b[c];
    const double lre = ea * cos(bb), lim = ea * sin(bb);
    float2 cin = cinArr[(size_t)ch * KDIM + m * 64 + c];
    double sre = (double)cin.x, sim = (double)cin.y;
#pragma unroll 4
    for (int j = 0; j < 64; ++j) {
        double g = (double)gb[j];
        if (fb[j]) { sre = g; sim = 0.0; }
        else {
            double nr = fma(sre, lre, fma(-sim, lim, g));
            double ni = fma(sre, lim, sim * lre);
            sre = nr; sim = ni;
        }
        unsigned short* strow = stbf + (size_t)(t0 + j) * K2;
        strow[m * 64 + c]        = f2bf((float)sre);
        strow[4096 + m * 64 + c] = f2bf((float)sim);
    }
    if (ch == 63) {   // t = 4095: final state, planar f32
        out[524288 + m * 64 + c]        = (float)sre;
        out[524288 + 4096 + m * 64 + c] = (float)sim;
    }
}

// ---------------------------------------------------------------- z GEMM: bf16 MFMA, M-tile 64, K-split x4
// grid: (mb 0..63) x (kb 0..3); 256 threads = 4 waves; wave w = rows w*16..w*16+15, all 4 n-tiles
__global__ __launch_bounds__(256) void k_zgemm(
    const unsigned short* __restrict__ stbf,
    const unsigned short* __restrict__ wzt,
    float* __restrict__ part)
{
    __shared__ char smem[65536];   // A: [64][512B] at 0, B: [64][512B] at 32768
    const int tid = threadIdx.x;
    const int w = tid >> 6, l = tid & 63;
    const int mb = blockIdx.x >> 2, kb = blockIdx.x & 3;
    const int kbase = kb * 2048;

    float4v acc[4];
#pragma unroll
    for (int i = 0; i < 4; ++i) acc[i] = (float4v){0.f, 0.f, 0.f, 0.f};

    for (int ks = 0; ks < 8; ++ks) {
        // ---- stage: 2048 16B-chunks for A, 2048 for B (linear LDS dest, swizzled global src)
#pragma unroll
        for (int it = 0; it < 8; ++it) {
            int ci = it * 256 + w * 64 + l;           // 0..2047
            int r = ci >> 5, pc = ci & 31;
            int gc = pc ^ (r & 7);
            const unsigned short* gpA = stbf + (size_t)(mb * 64 + r) * K2 + kbase + ks * 256 + gc * 8;
            const unsigned short* gpB = wzt + (size_t)r * K2 + kbase + ks * 256 + gc * 8;
            char* lpA = smem + (it * 256 + w * 64) * 16;
            char* lpB = smem + 32768 + (it * 256 + w * 64) * 16;
            __builtin_amdgcn_global_load_lds(
                (const __attribute__((address_space(1))) void*)gpA,
                (__attribute__((address_space(3))) void*)lpA, 16, 0, 0);
            __builtin_amdgcn_global_load_lds(
                (const __attribute__((address_space(1))) void*)gpB,
                (__attribute__((address_space(3))) void*)lpB, 16, 0, 0);
        }
        __syncthreads();
        // ---- compute 8 K-steps of 32
        const int row_l = w * 16 + (l & 15);
        const int swz = (l & 7) << 4;
        const int ksub = (l >> 4) * 16;
#pragma unroll
        for (int k32 = 0; k32 < 8; ++k32) {
            int kbyte = k32 * 64 + ksub;
            short8v af = *(short8v*)(smem + row_l * 512 + (kbyte ^ swz));
#pragma unroll
            for (int nt = 0; nt < 4; ++nt) {
                int row_b = nt * 16 + (l & 15);
                short8v bf = *(short8v*)(smem + 32768 + row_b * 512 + (kbyte ^ swz));
                acc[nt] = __builtin_amdgcn_mfma_f32_16x16x32_bf16(af, bf, acc[nt], 0, 0, 0);
            }
        }
        __syncthreads();
    }

    // C/D layout: col = lane&15, row = (lane>>4)*4 + reg
    float* pp = part + (size_t)kb * 262144;
    const int trow = mb * 64 + w * 16 + (l >> 4) * 4;
    const int jcol = l & 15;
#pragma unroll
    for (int nt = 0; nt < 4; ++nt)
#pragma unroll
        for (int r = 0; r < 4; ++r)
            pp[(size_t)(trow + r) * 64 + nt * 16 + jcol] = acc[nt][r];
}

// ---------------------------------------------------------------- epilogue
__device__ __forceinline__ float wsum(float v) {
#pragma unroll
    for (int o = 32; o; o >>= 1) v += __shfl_xor(v, o, 64);
    return v;
}

__global__ __launch_bounds__(256) void k_epi(
    const float* __restrict__ part, const float* __restrict__ bz,
    const float* __restrict__ go, const float* __restrict__ sk,
    const float* __restrict__ W3, const float* __restrict__ b3,
    const float* __restrict__ W4, const float* __restrict__ b4,
    float* __restrict__ out)
{
    __shared__ float ob[4][64], hb[4][64];
    const int w = threadIdx.x >> 6, j = threadIdx.x & 63;
    const int t = blockIdx.x * 4 + w;
    float z = bz[j];
#pragma unroll
    for (int p = 0; p < 4; ++p) z += part[(size_t)p * 262144 + t * 64 + j];
    float g = go[t * 64 + j];
    float y = z * g;
    float mu = wsum(y) * 0.015625f;
    float d = y - mu;
    float var = wsum(d * d) * 0.015625f;
    float o = d * (1.f / sqrtf(var + 1e-6f)) + sk[t * 64 + j] * (1.f - g);
    ob[w][j] = o;
    __syncthreads();
    float acc = b3[j];
#pragma unroll 8
    for (int k = 0; k < 64; ++k) acc += ob[w][k] * W3[k * 64 + j];
    hb[w][j] = fmaxf(acc, 0.f);
    __syncthreads();
    float o1 = b4[j], o2 = b4[j + 64];
#pragma unroll 8
    for (int k = 0; k < 64; ++k) { float hv = hb[w][k]; o1 += hv * W4[k * 128 + j]; o2 += hv * W4[k * 128 + j + 64]; }
    out[(size_t)t * 128 + j] = o1;
    out[(size_t)t * 128 + j + 64] = o2;
}

// ----------------------------------------------------------------
extern "C" void kernel_launch(void* const* d_in, const int* in_sizes, int n_in,
                              void* d_out, int out_size, void* d_ws, size_t ws_size,
                              hipStream_t stream)
{
    const float* x   = (const float*)d_in[0];
    const float* st0 = (const float*)d_in[1];
    const void*  start = d_in[2];
    const float* a  = (const float*)d_in[3];
    const float* b  = (const float*)d_in[4];
    const float* W1 = (const float*)d_in[5];  const float* b1 = (const float*)d_in[6];
    const float* W2 = (const float*)d_in[7];  const float* b2 = (const float*)d_in[8];
    const float* Wgi= (const float*)d_in[9];  const float* bgi= (const float*)d_in[10];
    const float* Wp = (const float*)d_in[11]; const float* bp = (const float*)d_in[12];
    const float* Wz = (const float*)d_in[13]; const float* bz = (const float*)d_in[14];
    const float* Wgo= (const float*)d_in[15]; const float* bgo= (const float*)d_in[16];
    const float* Wsk= (const float*)d_in[17]; const float* bsk= (const float*)d_in[18];
    const float* W3 = (const float*)d_in[19]; const float* b3 = (const float*)d_in[20];
    const float* W4 = (const float*)d_in[21]; const float* b4 = (const float*)d_in[22];

    float* ws    = (float*)d_ws;
    float* out   = (float*)d_out;
    float* gated = ws + OFF_GATED;
    float* go    = ws + OFF_GO;
    float* sk    = ws + OFF_SKIP;
    float* part  = ws + OFF_PART;
    int*   flags = (int*)(ws + OFF_FLAGS);
    int*   chs   = (int*)(ws + OFF_CHS);
    unsigned short* wzt  = (unsigned short*)(ws + OFF_WZT);
    unsigned short* stbf = (unsigned short*)(ws + OFF_STBF);

    float2* carryB = (float2*)(part);            // 524288 floats
    float2* cinArr = (float2*)(part + 524288);   // 524288 floats

    hipLaunchKernelGGL(k_flags, dim3(1), dim3(256), 0, stream,
                       (const unsigned char*)start, (const int*)start, flags, chs);
    hipLaunchKernelGGL(k_wzt, dim3(256), dim3(256), 0, stream, Wz, wzt);
    hipLaunchKernelGGL(k_mlp, dim3(256), dim3(256), 0, stream,
                       x, W1, b1, W2, b2, Wgi, bgi, Wp, bp, Wgo, bgo, Wsk, bsk,
                       gated, go, sk);
    hipLaunchKernelGGL(k_scanA, dim3(4096), dim3(64), 0, stream,
                       gated, flags, a, b, carryB);
    hipLaunchKernelGGL(k_scanC, dim3(64), dim3(64), 0, stream,
                       carryB, chs, a, b, st0, cinArr);
    hipLaunchKernelGGL(k_scanB, dim3(4096), dim3(64), 0, stream,
                       gated, flags, a, b, cinArr, stbf, out);
    hipLaunchKernelGGL(k_zgemm, dim3(256), dim3(256), 0, stream, stbf, wzt, part);
    hipLaunchKernelGGL(k_epi, dim3(1024), dim3(256), 0, stream,
                       part, bz, go, sk, W3, b3, W4, b4, out);
}

// Round 5
// 116.816 us; speedup vs baseline: 3.2424x; 1.2518x over previous
//
#include <hip/hip_runtime.h>
#include <math.h>

#define T_LEN 4096
#define D_IN 128
#define HID 64
#define KDIM 4096   // TR*CTX
#define K2   8192   // re+im

// ws float offsets
#define OFF_GATED 0u
#define OFF_GO    262144u
#define OFF_SKIP  524288u
#define OFF_PART  786432u          // 4 * 262144 partials (also scan-carry scratch)
#define OFF_FLAGS 1835008u         // 4096 ints
#define OFF_CHS   1839104u         // 64 ints
#define OFF_WZT   1839168u         // 524288 bf16 = 262144 float slots
#define OFF_STBF  2101312u         // 4096*8192 bf16 = 16777216 float slots

typedef __attribute__((ext_vector_type(8))) short short8v;
typedef __attribute__((ext_vector_type(4))) float float4v;

__device__ __forceinline__ float sigm(float x){ return 1.f/(1.f+expf(-x)); }
__device__ __forceinline__ unsigned short f2bf(float x){
    unsigned int u = __float_as_uint(x);
    return (unsigned short)((u + 0x7FFFu + ((u >> 16) & 1u)) >> 16);
}

// ---------------------------------------------------------------- start flags
__global__ __launch_bounds__(256) void k_flags(const unsigned char* __restrict__ su8,
                                               const int* __restrict__ si32,
                                               int* __restrict__ flags,
                                               int* __restrict__ chunkStart)
{
    __shared__ int cnt;
    const int tid = threadIdx.x;
    if (tid == 0) cnt = 0;
    __syncthreads();
    int local = 0;
    for (int i = tid; i < 4096; i += 256)
        if (i & 3) local += su8[i];
    if (local) atomicAdd(&cnt, local);
    __syncthreads();
    if (cnt > 0) {      // byte/bool storage
        for (int i = tid; i < 4096; i += 256) flags[i] = su8[i] ? 1 : 0;
    } else {            // int32 storage
        for (int i = tid; i < 4096; i += 256) flags[i] = si32[i] ? 1 : 0;
    }
    __syncthreads();
    if (tid < 64) {
        int any = 0;
#pragma unroll 8
        for (int j = 0; j < 64; ++j) any |= flags[tid * 64 + j];
        chunkStart[tid] = any;
    }
}

// ---------------------------------------------------------------- Wz -> bf16 transposed/permuted  WzT[64][8192]
__global__ __launch_bounds__(256) void k_wzt(const float* __restrict__ Wz,
                                             unsigned short* __restrict__ wzt)
{
    int idx = (blockIdx.x * 256 + threadIdx.x) * 8;   // 524288 elems
    int j = idx >> 13, k0 = idx & 8191;
#pragma unroll
    for (int e = 0; e < 8; ++e) {
        int k = k0 + e;
        int km = k & 4095;
        int m = km >> 6, c = km & 63;
        int row = m * 128 + ((k >= 4096) ? 64 : 0) + c;
        wzt[(size_t)j * K2 + k] = f2bf(Wz[(size_t)row * 64 + j]);
    }
}

// ---------------------------------------------------------------- MLP + gates: weights-in-VGPR, 8 rows/block
__global__ __launch_bounds__(512) void k_mlp(
    const float* __restrict__ x,
    const float* __restrict__ W1, const float* __restrict__ b1,
    const float* __restrict__ W2, const float* __restrict__ b2,
    const float* __restrict__ Wgi, const float* __restrict__ bgi,
    const float* __restrict__ Wp,  const float* __restrict__ bp,
    const float* __restrict__ Wgo, const float* __restrict__ bgo,
    const float* __restrict__ Wsk, const float* __restrict__ bsk,
    float* __restrict__ gated, float* __restrict__ go, float* __restrict__ sk)
{
    __shared__ float xs[8][128];
    __shared__ float hs[8][64];
    __shared__ float h2s[8][128];
    __shared__ float tmp[8][4][64];
    const int tid = threadIdx.x;
    const int t0 = blockIdx.x * 8;

    // stage 8 x-rows (1024 floats)
    if (tid < 256) {
        int r = tid >> 5, kq = (tid & 31) << 2;
        *(float4*)&xs[r][kq] = *(const float4*)&x[(size_t)(t0 + r) * D_IN + kq];
    }

    // ---- phase 1: h = relu(x@W1+b1). roles: j1 = tid>>3 in [0,64), ks1 = tid&7
    const int j1 = tid >> 3, ks1 = tid & 7;
    float wr1[16];
#pragma unroll
    for (int kk = 0; kk < 16; ++kk) wr1[kk] = W1[(size_t)(ks1 * 16 + kk) * HID + j1];
    const float bias1 = b1[j1];
    __syncthreads();
#pragma unroll
    for (int r = 0; r < 8; ++r) {
        float p = 0.f;
#pragma unroll
        for (int kq = 0; kq < 4; ++kq) {
            float4 xv = *(const float4*)&xs[r][ks1 * 16 + kq * 4];
            p += xv.x * wr1[kq*4] + xv.y * wr1[kq*4+1] + xv.z * wr1[kq*4+2] + xv.w * wr1[kq*4+3];
        }
        p += __shfl_xor(p, 1, 64); p += __shfl_xor(p, 2, 64); p += __shfl_xor(p, 4, 64);
        if (ks1 == 0) hs[r][j1] = fmaxf(p + bias1, 0.f);
    }

    // ---- phase 2: h2 = h@W2+b2. roles: j2 = tid>>2 in [0,128), ks2 = tid&3
    const int j2 = tid >> 2, ks2 = tid & 3;
    float wr2[16];
#pragma unroll
    for (int kk = 0; kk < 16; ++kk) wr2[kk] = W2[(size_t)(ks2 * 16 + kk) * 128 + j2];
    const float bias2 = b2[j2];
    __syncthreads();
#pragma unroll
    for (int r = 0; r < 8; ++r) {
        float p = 0.f;
#pragma unroll
        for (int kq = 0; kq < 4; ++kq) {
            float4 hv = *(const float4*)&hs[r][ks2 * 16 + kq * 4];
            p += hv.x * wr2[kq*4] + hv.y * wr2[kq*4+1] + hv.z * wr2[kq*4+2] + hv.w * wr2[kq*4+3];
        }
        p += __shfl_xor(p, 1, 64); p += __shfl_xor(p, 2, 64);
        if (ks2 == 0) h2s[r][j2] = p + bias2;
    }

    // ---- phase 3: four gate GEMMs (128->64). roles: mat = tid>>7 (wave-uniform), jj, kh
    const int mat = tid >> 7, jj = (tid & 127) >> 1, kh = tid & 1;
    const float* Wm = (mat == 0) ? Wgi : (mat == 1) ? Wp : (mat == 2) ? Wgo : Wsk;
    float wgr[64];
#pragma unroll
    for (int kk = 0; kk < 64; ++kk) wgr[kk] = Wm[(size_t)(kh * 64 + kk) * 64 + jj];
    __syncthreads();
#pragma unroll
    for (int r = 0; r < 8; ++r) {
        float p = 0.f;
#pragma unroll
        for (int kq = 0; kq < 16; ++kq) {
            float4 hv = *(const float4*)&h2s[r][kh * 64 + kq * 4];
            p += hv.x * wgr[kq*4] + hv.y * wgr[kq*4+1] + hv.z * wgr[kq*4+2] + hv.w * wgr[kq*4+3];
        }
        p += __shfl_xor(p, 1, 64);
        if (kh == 0) tmp[r][mat][jj] = p;
    }
    __syncthreads();

    // ---- finalize: tid = r*64 + j
    {
        int r = tid >> 6, j = tid & 63;
        int t = t0 + r;
        float gi = sigm(tmp[r][0][j] + bgi[j]);
        float pr = sigm(tmp[r][1][j] + bp[j]);
        float g  = sigm(tmp[r][2][j] + bgo[j]);
        float s  = tmp[r][3][j] + bsk[j];
        gated[t * 64 + j] = gi * pr;
        go[t * 64 + j]    = g;
        sk[t * 64 + j]    = s;
    }
}

// ---------------------------------------------------------------- scan A: per-chunk local carries
__global__ __launch_bounds__(64) void k_scanA(
    const float* __restrict__ gated, const int* __restrict__ flags,
    const float* __restrict__ a, const float* __restrict__ b,
    float2* __restrict__ carryB)
{
    const int bx = blockIdx.x;
    const int ch = bx & 63, m = bx >> 6;
    const int c = threadIdx.x;
    const int t0 = ch * 64;
    __shared__ float gb[64];
    __shared__ int fb[64];
    gb[c] = gated[(size_t)(t0 + c) * 64 + m];
    fb[c] = flags[t0 + c];
    __syncthreads();

    const double ea = exp(-fabs((double)a[m]));
    const double bb = (double)b[c];
    const double lre = ea * cos(bb), lim = ea * sin(bb);
    double sre = 0.0, sim = 0.0;
#pragma unroll 8
    for (int j = 0; j < 64; ++j) {
        double g = (double)gb[j];
        if (fb[j]) { sre = g; sim = 0.0; }
        else {
            double nr = fma(sre, lre, fma(-sim, lim, g));
            double ni = fma(sre, lim, sim * lre);
            sre = nr; sim = ni;
        }
    }
    carryB[(size_t)ch * KDIM + m * 64 + c] = make_float2((float)sre, (float)sim);
}

// ---------------------------------------------------------------- scan C: carry scan over chunks
__global__ __launch_bounds__(64) void k_scanC(
    const float2* __restrict__ carryB, const int* __restrict__ chunkStart,
    const float* __restrict__ a, const float* __restrict__ b,
    const float* __restrict__ st0,
    float2* __restrict__ cinArr)
{
    const int m = blockIdx.x, c = threadIdx.x;
    const double ea64 = exp(-64.0 * fabs((double)a[m]));
    const double bb = (double)b[c];
    const double l64re = ea64 * cos(64.0 * bb), l64im = ea64 * sin(64.0 * bb);
    double cre = (double)st0[(m * 64 + c) * 2];
    double cim = (double)st0[(m * 64 + c) * 2 + 1];
    for (int ch = 0; ch < 64; ++ch) {
        cinArr[(size_t)ch * KDIM + m * 64 + c] = make_float2((float)cre, (float)cim);
        float2 B = carryB[(size_t)ch * KDIM + m * 64 + c];
        if (chunkStart[ch]) { cre = (double)B.x; cim = (double)B.y; }
        else {
            double nr = fma(cre, l64re, fma(-cim, l64im, (double)B.x));
            double ni = fma(cre, l64im, fma(cim, l64re, (double)B.y));
            cre = nr; cim = ni;
        }
    }
}

// ---------------------------------------------------------------- scan B: seeded rerun, write bf16 state (+ final state f32)
__global__ __launch_bounds__(64) void k_scanB(
    const float* __restrict__ gated, const int* __restrict__ flags,
    const float* __restrict__ a, const float* __restrict__ b,
    const float2* __restrict__ cinArr,
    unsigned short* __restrict__ stbf,
    float* __restrict__ out)
{
    const int bx = blockIdx.x;
    const int ch = bx & 63, m = bx >> 6;
    const int c = threadIdx.x;
    const int t0 = ch * 64;
    __shared__ float gb[64];
    __shared__ int fb[64];
    gb[c] = gated[(size_t)(t0 + c) * 64 + m];
    fb[c] = flags[t0 + c];
    __syncthreads();

    const double ea = exp(-fabs((double)a[m]));
    const double bb = (double)b[c];
    const double lre = ea * cos(bb), lim = ea * sin(bb);
    float2 cin = cinArr[(size_t)ch * KDIM + m * 64 + c];
    double sre = (double)cin.x, sim = (double)cin.y;
#pragma unroll 4
    for (int j = 0; j < 64; ++j) {
        double g = (double)gb[j];
        if (fb[j]) { sre = g; sim = 0.0; }
        else {
            double nr = fma(sre, lre, fma(-sim, lim, g));
            double ni = fma(sre, lim, sim * lre);
            sre = nr; sim = ni;
        }
        unsigned short* strow = stbf + (size_t)(t0 + j) * K2;
        strow[m * 64 + c]        = f2bf((float)sre);
        strow[4096 + m * 64 + c] = f2bf((float)sim);
    }
    if (ch == 63) {   // t = 4095: final state, planar f32
        out[524288 + m * 64 + c]        = (float)sre;
        out[524288 + 4096 + m * 64 + c] = (float)sim;
    }
}

// ---------------------------------------------------------------- z GEMM: bf16 MFMA, M-tile 64, K-split x4
__global__ __launch_bounds__(256) void k_zgemm(
    const unsigned short* __restrict__ stbf,
    const unsigned short* __restrict__ wzt,
    float* __restrict__ part)
{
    __shared__ char smem[65536];   // A: [64][512B] at 0, B: [64][512B] at 32768
    const int tid = threadIdx.x;
    const int w = tid >> 6, l = tid & 63;
    const int mb = blockIdx.x >> 2, kb = blockIdx.x & 3;
    const int kbase = kb * 2048;

    float4v acc[4];
#pragma unroll
    for (int i = 0; i < 4; ++i) acc[i] = (float4v){0.f, 0.f, 0.f, 0.f};

    for (int ks = 0; ks < 8; ++ks) {
#pragma unroll
        for (int it = 0; it < 8; ++it) {
            int ci = it * 256 + w * 64 + l;           // 0..2047
            int r = ci >> 5, pc = ci & 31;
            int gc = pc ^ (r & 7);
            const unsigned short* gpA = stbf + (size_t)(mb * 64 + r) * K2 + kbase + ks * 256 + gc * 8;
            const unsigned short* gpB = wzt + (size_t)r * K2 + kbase + ks * 256 + gc * 8;
            char* lpA = smem + (it * 256 + w * 64) * 16;
            char* lpB = smem + 32768 + (it * 256 + w * 64) * 16;
            __builtin_amdgcn_global_load_lds(
                (const __attribute__((address_space(1))) void*)gpA,
                (__attribute__((address_space(3))) void*)lpA, 16, 0, 0);
            __builtin_amdgcn_global_load_lds(
                (const __attribute__((address_space(1))) void*)gpB,
                (__attribute__((address_space(3))) void*)lpB, 16, 0, 0);
        }
        __syncthreads();
        const int row_l = w * 16 + (l & 15);
        const int swz = (l & 7) << 4;
        const int ksub = (l >> 4) * 16;
#pragma unroll
        for (int k32 = 0; k32 < 8; ++k32) {
            int kbyte = k32 * 64 + ksub;
            short8v af = *(short8v*)(smem + row_l * 512 + (kbyte ^ swz));
#pragma unroll
            for (int nt = 0; nt < 4; ++nt) {
                int row_b = nt * 16 + (l & 15);
                short8v bf = *(short8v*)(smem + 32768 + row_b * 512 + (kbyte ^ swz));
                acc[nt] = __builtin_amdgcn_mfma_f32_16x16x32_bf16(af, bf, acc[nt], 0, 0, 0);
            }
        }
        __syncthreads();
    }

    float* pp = part + (size_t)kb * 262144;
    const int trow = mb * 64 + w * 16 + (l >> 4) * 4;
    const int jcol = l & 15;
#pragma unroll
    for (int nt = 0; nt < 4; ++nt)
#pragma unroll
        for (int r = 0; r < 4; ++r)
            pp[(size_t)(trow + r) * 64 + nt * 16 + jcol] = acc[nt][r];
}

// ---------------------------------------------------------------- epilogue
__device__ __forceinline__ float wsum(float v) {
#pragma unroll
    for (int o = 32; o; o >>= 1) v += __shfl_xor(v, o, 64);
    return v;
}

__global__ __launch_bounds__(256) void k_epi(
    const float* __restrict__ part, const float* __restrict__ bz,
    const float* __restrict__ go, const float* __restrict__ sk,
    const float* __restrict__ W3, const float* __restrict__ b3,
    const float* __restrict__ W4, const float* __restrict__ b4,
    float* __restrict__ out)
{
    __shared__ float ob[4][64], hb[4][64];
    const int w = threadIdx.x >> 6, j = threadIdx.x & 63;
    const int t = blockIdx.x * 4 + w;
    float z = bz[j];
#pragma unroll
    for (int p = 0; p < 4; ++p) z += part[(size_t)p * 262144 + t * 64 + j];
    float g = go[t * 64 + j];
    float y = z * g;
    float mu = wsum(y) * 0.015625f;
    float d = y - mu;
    float var = wsum(d * d) * 0.015625f;
    float o = d * (1.f / sqrtf(var + 1e-6f)) + sk[t * 64 + j] * (1.f - g);
    ob[w][j] = o;
    __syncthreads();
    float acc = b3[j];
#pragma unroll 8
    for (int k = 0; k < 64; ++k) acc += ob[w][k] * W3[k * 64 + j];
    hb[w][j] = fmaxf(acc, 0.f);
    __syncthreads();
    float o1 = b4[j], o2 = b4[j + 64];
#pragma unroll 8
    for (int k = 0; k < 64; ++k) { float hv = hb[w][k]; o1 += hv * W4[k * 128 + j]; o2 += hv * W4[k * 128 + j + 64]; }
    out[(size_t)t * 128 + j] = o1;
    out[(size_t)t * 128 + j + 64] = o2;
}

// ----------------------------------------------------------------
extern "C" void kernel_launch(void* const* d_in, const int* in_sizes, int n_in,
                              void* d_out, int out_size, void* d_ws, size_t ws_size,
                              hipStream_t stream)
{
    const float* x   = (const float*)d_in[0];
    const float* st0 = (const float*)d_in[1];
    const void*  start = d_in[2];
    const float* a  = (const float*)d_in[3];
    const float* b  = (const float*)d_in[4];
    const float* W1 = (const float*)d_in[5];  const float* b1 = (const float*)d_in[6];
    const float* W2 = (const float*)d_in[7];  const float* b2 = (const float*)d_in[8];
    const float* Wgi= (const float*)d_in[9];  const float* bgi= (const float*)d_in[10];
    const float* Wp = (const float*)d_in[11]; const float* bp = (const float*)d_in[12];
    const float* Wz = (const float*)d_in[13]; const float* bz = (const float*)d_in[14];
    const float* Wgo= (const float*)d_in[15]; const float* bgo= (const float*)d_in[16];
    const float* Wsk= (const float*)d_in[17]; const float* bsk= (const float*)d_in[18];
    const float* W3 = (const float*)d_in[19]; const float* b3 = (const float*)d_in[20];
    const float* W4 = (const float*)d_in[21]; const float* b4 = (const float*)d_in[22];

    float* ws    = (float*)d_ws;
    float* out   = (float*)d_out;
    float* gated = ws + OFF_GATED;
    float* go    = ws + OFF_GO;
    float* sk    = ws + OFF_SKIP;
    float* part  = ws + OFF_PART;
    int*   flags = (int*)(ws + OFF_FLAGS);
    int*   chs   = (int*)(ws + OFF_CHS);
    unsigned short* wzt  = (unsigned short*)(ws + OFF_WZT);
    unsigned short* stbf = (unsigned short*)(ws + OFF_STBF);

    float2* carryB = (float2*)(part);            // 524288 floats
    float2* cinArr = (float2*)(part + 524288);   // 524288 floats

    hipLaunchKernelGGL(k_flags, dim3(1), dim3(256), 0, stream,
                       (const unsigned char*)start, (const int*)start, flags, chs);
    hipLaunchKernelGGL(k_wzt, dim3(256), dim3(256), 0, stream, Wz, wzt);
    hipLaunchKernelGGL(k_mlp, dim3(512), dim3(512), 0, stream,
                       x, W1, b1, W2, b2, Wgi, bgi, Wp, bp, Wgo, bgo, Wsk, bsk,
                       gated, go, sk);
    hipLaunchKernelGGL(k_scanA, dim3(4096), dim3(64), 0, stream,
                       gated, flags, a, b, carryB);
    hipLaunchKernelGGL(k_scanC, dim3(64), dim3(64), 0, stream,
                       carryB, chs, a, b, st0, cinArr);
    hipLaunchKernelGGL(k_scanB, dim3(4096), dim3(64), 0, stream,
                       gated, flags, a, b, cinArr, stbf, out);
    hipLaunchKernelGGL(k_zgemm, dim3(256), dim3(256), 0, stream, stbf, wzt, part);
    hipLaunchKernelGGL(k_epi, dim3(1024), dim3(256), 0, stream,
                       part, bz, go, sk, W3, b3, W4, b4, out);
}

// Round 6
// 92.187 us; speedup vs baseline: 4.1086x; 1.2672x over previous
//
#include <hip/hip_runtime.h>
#include <math.h>

#define T_LEN 4096
#define D_IN 128
#define HID 64
#define KDIM 4096   // TR*CTX
#define K2   8192   // re+im

// ws float offsets
#define OFF_GATED 0u
#define OFF_GO    262144u
#define OFF_SKIP  524288u
#define OFF_PART  786432u          // 8 * 262144 partials (also scan-carry scratch)
#define OFF_FLAGS 2883584u         // 4096 ints
#define OFF_CHS   2887680u         // 64 ints
#define OFF_WZT   2887744u         // 524288 bf16 = 262144 float slots
#define OFF_STBF  3149888u         // 4096*8192 bf16 = 16777216 float slots

typedef __attribute__((ext_vector_type(8))) short short8v;
typedef __attribute__((ext_vector_type(4))) float float4v;

__device__ __forceinline__ float sigm(float x){ return 1.f/(1.f+expf(-x)); }
__device__ __forceinline__ unsigned short f2bf(float x){
    unsigned int u = __float_as_uint(x);
    return (unsigned short)((u + 0x7FFFu + ((u >> 16) & 1u)) >> 16);
}

// ---------------------------------------------------------------- prep: flags | wzt | mlp  (role by blockIdx)
__global__ __launch_bounds__(512) void k_prep(
    const unsigned char* __restrict__ su8, const int* __restrict__ si32,
    int* __restrict__ flags, int* __restrict__ chunkStart,
    const float* __restrict__ Wz, unsigned short* __restrict__ wzt,
    const float* __restrict__ x,
    const float* __restrict__ W1, const float* __restrict__ b1,
    const float* __restrict__ W2, const float* __restrict__ b2,
    const float* __restrict__ Wgi, const float* __restrict__ bgi,
    const float* __restrict__ Wp,  const float* __restrict__ bp,
    const float* __restrict__ Wgo, const float* __restrict__ bgo,
    const float* __restrict__ Wsk, const float* __restrict__ bsk,
    float* __restrict__ gated, float* __restrict__ go, float* __restrict__ sk)
{
    const int bx = blockIdx.x;
    const int tid = threadIdx.x;

    if (bx == 0) {
        // ---------------- flags
        __shared__ int cnt;
        if (tid == 0) cnt = 0;
        __syncthreads();
        int local = 0;
        for (int i = tid; i < 4096; i += 512)
            if (i & 3) local += su8[i];
        if (local) atomicAdd(&cnt, local);
        __syncthreads();
        if (cnt > 0) {      // byte/bool storage
            for (int i = tid; i < 4096; i += 512) flags[i] = su8[i] ? 1 : 0;
        } else {            // int32 storage
            for (int i = tid; i < 4096; i += 512) flags[i] = si32[i] ? 1 : 0;
        }
        __syncthreads();
        if (tid < 64) {
            int any = 0;
#pragma unroll 8
            for (int j = 0; j < 64; ++j) any |= flags[tid * 64 + j];
            chunkStart[tid] = any;
        }
        return;
    }
    if (bx <= 64) {
        // ---------------- wzt: WzT[64][8192] bf16
        int idx = ((bx - 1) * 512 + tid) * 16;
        int j = idx >> 13, k0 = idx & 8191;
#pragma unroll
        for (int e = 0; e < 16; ++e) {
            int k = k0 + e;
            int km = k & 4095;
            int m = km >> 6, c = km & 63;
            int row = m * 128 + ((k >= 4096) ? 64 : 0) + c;
            wzt[(size_t)j * K2 + k] = f2bf(Wz[(size_t)row * 64 + j]);
        }
        return;
    }

    // ---------------- mlp: 8 rows per block, weights-in-VGPR
    __shared__ float xs[8][128];
    __shared__ float hs[8][64];
    __shared__ float h2s[8][128];
    __shared__ float tmp[8][4][64];
    const int t0 = (bx - 65) * 8;

    if (tid < 256) {
        int r = tid >> 5, kq = (tid & 31) << 2;
        *(float4*)&xs[r][kq] = *(const float4*)&x[(size_t)(t0 + r) * D_IN + kq];
    }

    // phase 1: h = relu(x@W1+b1). j1 in [0,64), ks1 = tid&7
    const int j1 = tid >> 3, ks1 = tid & 7;
    float wr1[16];
#pragma unroll
    for (int kk = 0; kk < 16; ++kk) wr1[kk] = W1[(size_t)(ks1 * 16 + kk) * HID + j1];
    const float bias1 = b1[j1];
    __syncthreads();
#pragma unroll
    for (int r = 0; r < 8; ++r) {
        float p = 0.f;
#pragma unroll
        for (int kq = 0; kq < 4; ++kq) {
            float4 xv = *(const float4*)&xs[r][ks1 * 16 + kq * 4];
            p += xv.x * wr1[kq*4] + xv.y * wr1[kq*4+1] + xv.z * wr1[kq*4+2] + xv.w * wr1[kq*4+3];
        }
        p += __shfl_xor(p, 1, 64); p += __shfl_xor(p, 2, 64); p += __shfl_xor(p, 4, 64);
        if (ks1 == 0) hs[r][j1] = fmaxf(p + bias1, 0.f);
    }

    // phase 2: h2 = h@W2+b2. j2 in [0,128), ks2 = tid&3
    const int j2 = tid >> 2, ks2 = tid & 3;
    float wr2[16];
#pragma unroll
    for (int kk = 0; kk < 16; ++kk) wr2[kk] = W2[(size_t)(ks2 * 16 + kk) * 128 + j2];
    const float bias2 = b2[j2];
    __syncthreads();
#pragma unroll
    for (int r = 0; r < 8; ++r) {
        float p = 0.f;
#pragma unroll
        for (int kq = 0; kq < 4; ++kq) {
            float4 hv = *(const float4*)&hs[r][ks2 * 16 + kq * 4];
            p += hv.x * wr2[kq*4] + hv.y * wr2[kq*4+1] + hv.z * wr2[kq*4+2] + hv.w * wr2[kq*4+3];
        }
        p += __shfl_xor(p, 1, 64); p += __shfl_xor(p, 2, 64);
        if (ks2 == 0) h2s[r][j2] = p + bias2;
    }

    // phase 3: four gate GEMMs (128->64). mat = tid>>7 (wave-uniform), jj, kh
    const int mat = tid >> 7, jj = (tid & 127) >> 1, kh = tid & 1;
    const float* Wm = (mat == 0) ? Wgi : (mat == 1) ? Wp : (mat == 2) ? Wgo : Wsk;
    float wgr[64];
#pragma unroll
    for (int kk = 0; kk < 64; ++kk) wgr[kk] = Wm[(size_t)(kh * 64 + kk) * 64 + jj];
    __syncthreads();
#pragma unroll
    for (int r = 0; r < 8; ++r) {
        float p = 0.f;
#pragma unroll
        for (int kq = 0; kq < 16; ++kq) {
            float4 hv = *(const float4*)&h2s[r][kh * 64 + kq * 4];
            p += hv.x * wgr[kq*4] + hv.y * wgr[kq*4+1] + hv.z * wgr[kq*4+2] + hv.w * wgr[kq*4+3];
        }
        p += __shfl_xor(p, 1, 64);
        if (kh == 0) tmp[r][mat][jj] = p;
    }
    __syncthreads();

    // finalize
    {
        int r = tid >> 6, j = tid & 63;
        int t = t0 + r;
        float gi = sigm(tmp[r][0][j] + bgi[j]);
        float pr = sigm(tmp[r][1][j] + bp[j]);
        float g  = sigm(tmp[r][2][j] + bgo[j]);
        float s  = tmp[r][3][j] + bsk[j];
        gated[t * 64 + j] = gi * pr;
        go[t * 64 + j]    = g;
        sk[t * 64 + j]    = s;
    }
}

// ---------------------------------------------------------------- scan A: per-chunk local carries (8 chains/block)
__global__ __launch_bounds__(512) void k_scanA(
    const float* __restrict__ gated, const int* __restrict__ flags,
    const float* __restrict__ a, const float* __restrict__ b,
    float2* __restrict__ carryB)
{
    const int p = threadIdx.x >> 6, c = threadIdx.x & 63;
    const int pair = blockIdx.x * 8 + p;
    const int ch = pair & 63, m = pair >> 6;
    const int t0 = ch * 64;
    __shared__ float gb[8][64];
    __shared__ int fb[8][64];
    gb[p][c] = gated[(size_t)(t0 + c) * 64 + m];
    fb[p][c] = flags[t0 + c];
    __syncthreads();

    const double ea = exp(-fabs((double)a[m]));
    const double bb = (double)b[c];
    const double lre = ea * cos(bb), lim = ea * sin(bb);
    double sre = 0.0, sim = 0.0;
#pragma unroll 8
    for (int j = 0; j < 64; ++j) {
        double g = (double)gb[p][j];
        if (fb[p][j]) { sre = g; sim = 0.0; }
        else {
            double nr = fma(sre, lre, fma(-sim, lim, g));
            double ni = fma(sre, lim, sim * lre);
            sre = nr; sim = ni;
        }
    }
    carryB[(size_t)ch * KDIM + m * 64 + c] = make_float2((float)sre, (float)sim);
}

// ---------------------------------------------------------------- scan C: carry scan over chunks (register-pipelined)
__global__ __launch_bounds__(64) void k_scanC(
    const float2* __restrict__ carryB, const int* __restrict__ chunkStart,
    const float* __restrict__ a, const float* __restrict__ b,
    const float* __restrict__ st0,
    float2* __restrict__ cinArr)
{
    const int m = blockIdx.x, c = threadIdx.x;
    __shared__ int chsS[64];
    chsS[c] = chunkStart[c];

    // load all 64 carries up front (independent loads)
    float2 Bv[64];
#pragma unroll
    for (int ch = 0; ch < 64; ++ch)
        Bv[ch] = carryB[(size_t)ch * KDIM + m * 64 + c];
    __syncthreads();

    const double ea64 = exp(-64.0 * fabs((double)a[m]));
    const double bb = (double)b[c];
    const double l64re = ea64 * cos(64.0 * bb), l64im = ea64 * sin(64.0 * bb);
    double cre = (double)st0[(m * 64 + c) * 2];
    double cim = (double)st0[(m * 64 + c) * 2 + 1];
#pragma unroll
    for (int ch = 0; ch < 64; ++ch) {
        cinArr[(size_t)ch * KDIM + m * 64 + c] = make_float2((float)cre, (float)cim);
        if (chsS[ch]) { cre = (double)Bv[ch].x; cim = (double)Bv[ch].y; }
        else {
            double nr = fma(cre, l64re, fma(-cim, l64im, (double)Bv[ch].x));
            double ni = fma(cre, l64im, fma(cim, l64re, (double)Bv[ch].y));
            cre = nr; cim = ni;
        }
    }
}

// ---------------------------------------------------------------- scan B: seeded rerun, write bf16 state (8 chains/block)
__global__ __launch_bounds__(512) void k_scanB(
    const float* __restrict__ gated, const int* __restrict__ flags,
    const float* __restrict__ a, const float* __restrict__ b,
    const float2* __restrict__ cinArr,
    unsigned short* __restrict__ stbf,
    float* __restrict__ out)
{
    const int p = threadIdx.x >> 6, c = threadIdx.x & 63;
    const int pair = blockIdx.x * 8 + p;
    const int ch = pair & 63, m = pair >> 6;
    const int t0 = ch * 64;
    __shared__ float gb[8][64];
    __shared__ int fb[8][64];
    gb[p][c] = gated[(size_t)(t0 + c) * 64 + m];
    fb[p][c] = flags[t0 + c];
    __syncthreads();

    const double ea = exp(-fabs((double)a[m]));
    const double bb = (double)b[c];
    const double lre = ea * cos(bb), lim = ea * sin(bb);
    float2 cin = cinArr[(size_t)ch * KDIM + m * 64 + c];
    double sre = (double)cin.x, sim = (double)cin.y;
#pragma unroll 4
    for (int j = 0; j < 64; ++j) {
        double g = (double)gb[p][j];
        if (fb[p][j]) { sre = g; sim = 0.0; }
        else {
            double nr = fma(sre, lre, fma(-sim, lim, g));
            double ni = fma(sre, lim, sim * lre);
            sre = nr; sim = ni;
        }
        unsigned short* strow = stbf + (size_t)(t0 + j) * K2;
        strow[m * 64 + c]        = f2bf((float)sre);
        strow[4096 + m * 64 + c] = f2bf((float)sim);
    }
    if (ch == 63) {   // t = 4095: final state, planar f32
        out[524288 + m * 64 + c]        = (float)sre;
        out[524288 + 4096 + m * 64 + c] = (float)sim;
    }
}

// ---------------------------------------------------------------- z GEMM: bf16 MFMA, M-tile 64, K-split x8
__global__ __launch_bounds__(256) void k_zgemm(
    const unsigned short* __restrict__ stbf,
    const unsigned short* __restrict__ wzt,
    float* __restrict__ part)
{
    __shared__ char smem[65536];   // A: [64][512B] at 0, B: [64][512B] at 32768
    const int tid = threadIdx.x;
    const int w = tid >> 6, l = tid & 63;
    const int mb = blockIdx.x >> 3, kb = blockIdx.x & 7;
    const int kbase = kb * 1024;

    float4v acc[4];
#pragma unroll
    for (int i = 0; i < 4; ++i) acc[i] = (float4v){0.f, 0.f, 0.f, 0.f};

    for (int ks = 0; ks < 4; ++ks) {
#pragma unroll
        for (int it = 0; it < 8; ++it) {
            int ci = it * 256 + w * 64 + l;           // 0..2047
            int r = ci >> 5, pc = ci & 31;
            int gc = pc ^ (r & 7);
            const unsigned short* gpA = stbf + (size_t)(mb * 64 + r) * K2 + kbase + ks * 256 + gc * 8;
            const unsigned short* gpB = wzt + (size_t)r * K2 + kbase + ks * 256 + gc * 8;
            char* lpA = smem + (it * 256 + w * 64) * 16;
            char* lpB = smem + 32768 + (it * 256 + w * 64) * 16;
            __builtin_amdgcn_global_load_lds(
                (const __attribute__((address_space(1))) void*)gpA,
                (__attribute__((address_space(3))) void*)lpA, 16, 0, 0);
            __builtin_amdgcn_global_load_lds(
                (const __attribute__((address_space(1))) void*)gpB,
                (__attribute__((address_space(3))) void*)lpB, 16, 0, 0);
        }
        __syncthreads();
        const int row_l = w * 16 + (l & 15);
        const int swz = (l & 7) << 4;
        const int ksub = (l >> 4) * 16;
#pragma unroll
        for (int k32 = 0; k32 < 8; ++k32) {
            int kbyte = k32 * 64 + ksub;
            short8v af = *(short8v*)(smem + row_l * 512 + (kbyte ^ swz));
#pragma unroll
            for (int nt = 0; nt < 4; ++nt) {
                int row_b = nt * 16 + (l & 15);
                short8v bf = *(short8v*)(smem + 32768 + row_b * 512 + (kbyte ^ swz));
                acc[nt] = __builtin_amdgcn_mfma_f32_16x16x32_bf16(af, bf, acc[nt], 0, 0, 0);
            }
        }
        __syncthreads();
    }

    float* pp = part + (size_t)kb * 262144;
    const int trow = mb * 64 + w * 16 + (l >> 4) * 4;
    const int jcol = l & 15;
#pragma unroll
    for (int nt = 0; nt < 4; ++nt)
#pragma unroll
        for (int r = 0; r < 4; ++r)
            pp[(size_t)(trow + r) * 64 + nt * 16 + jcol] = acc[nt][r];
}

// ---------------------------------------------------------------- epilogue
__device__ __forceinline__ float wsum(float v) {
#pragma unroll
    for (int o = 32; o; o >>= 1) v += __shfl_xor(v, o, 64);
    return v;
}

__global__ __launch_bounds__(256) void k_epi(
    const float* __restrict__ part, const float* __restrict__ bz,
    const float* __restrict__ go, const float* __restrict__ sk,
    const float* __restrict__ W3, const float* __restrict__ b3,
    const float* __restrict__ W4, const float* __restrict__ b4,
    float* __restrict__ out)
{
    __shared__ float ob[4][64], hb[4][64];
    const int w = threadIdx.x >> 6, j = threadIdx.x & 63;
    const int t = blockIdx.x * 4 + w;
    float z = bz[j];
#pragma unroll
    for (int p = 0; p < 8; ++p) z += part[(size_t)p * 262144 + t * 64 + j];
    float g = go[t * 64 + j];
    float y = z * g;
    float mu = wsum(y) * 0.015625f;
    float d = y - mu;
    float var = wsum(d * d) * 0.015625f;
    float o = d * (1.f / sqrtf(var + 1e-6f)) + sk[t * 64 + j] * (1.f - g);
    ob[w][j] = o;
    __syncthreads();
    float acc = b3[j];
#pragma unroll 8
    for (int k = 0; k < 64; ++k) acc += ob[w][k] * W3[k * 64 + j];
    hb[w][j] = fmaxf(acc, 0.f);
    __syncthreads();
    float o1 = b4[j], o2 = b4[j + 64];
#pragma unroll 8
    for (int k = 0; k < 64; ++k) { float hv = hb[w][k]; o1 += hv * W4[k * 128 + j]; o2 += hv * W4[k * 128 + j + 64]; }
    out[(size_t)t * 128 + j] = o1;
    out[(size_t)t * 128 + j + 64] = o2;
}

// ----------------------------------------------------------------
extern "C" void kernel_launch(void* const* d_in, const int* in_sizes, int n_in,
                              void* d_out, int out_size, void* d_ws, size_t ws_size,
                              hipStream_t stream)
{
    const float* x   = (const float*)d_in[0];
    const float* st0 = (const float*)d_in[1];
    const void*  start = d_in[2];
    const float* a  = (const float*)d_in[3];
    const float* b  = (const float*)d_in[4];
    const float* W1 = (const float*)d_in[5];  const float* b1 = (const float*)d_in[6];
    const float* W2 = (const float*)d_in[7];  const float* b2 = (const float*)d_in[8];
    const float* Wgi= (const float*)d_in[9];  const float* bgi= (const float*)d_in[10];
    const float* Wp = (const float*)d_in[11]; const float* bp = (const float*)d_in[12];
    const float* Wz = (const float*)d_in[13]; const float* bz = (const float*)d_in[14];
    const float* Wgo= (const float*)d_in[15]; const float* bgo= (const float*)d_in[16];
    const float* Wsk= (const float*)d_in[17]; const float* bsk= (const float*)d_in[18];
    const float* W3 = (const float*)d_in[19]; const float* b3 = (const float*)d_in[20];
    const float* W4 = (const float*)d_in[21]; const float* b4 = (const float*)d_in[22];

    float* ws    = (float*)d_ws;
    float* out   = (float*)d_out;
    float* gated = ws + OFF_GATED;
    float* go    = ws + OFF_GO;
    float* sk    = ws + OFF_SKIP;
    float* part  = ws + OFF_PART;
    int*   flags = (int*)(ws + OFF_FLAGS);
    int*   chs   = (int*)(ws + OFF_CHS);
    unsigned short* wzt  = (unsigned short*)(ws + OFF_WZT);
    unsigned short* stbf = (unsigned short*)(ws + OFF_STBF);

    float2* carryB = (float2*)(part);            // 524288 floats
    float2* cinArr = (float2*)(part + 524288);   // 524288 floats

    hipLaunchKernelGGL(k_prep, dim3(577), dim3(512), 0, stream,
                       (const unsigned char*)start, (const int*)start, flags, chs,
                       Wz, wzt, x, W1, b1, W2, b2, Wgi, bgi, Wp, bp,
                       Wgo, bgo, Wsk, bsk, gated, go, sk);
    hipLaunchKernelGGL(k_scanA, dim3(512), dim3(512), 0, stream,
                       gated, flags, a, b, carryB);
    hipLaunchKernelGGL(k_scanC, dim3(64), dim3(64), 0, stream,
                       carryB, chs, a, b, st0, cinArr);
    hipLaunchKernelGGL(k_scanB, dim3(512), dim3(512), 0, stream,
                       gated, flags, a, b, cinArr, stbf, out);
    hipLaunchKernelGGL(k_zgemm, dim3(512), dim3(256), 0, stream, stbf, wzt, part);
    hipLaunchKernelGGL(k_epi, dim3(1024), dim3(256), 0, stream,
                       part, bz, go, sk, W3, b3, W4, b4, out);
}